// Round 1
// baseline (2089.395 us; speedup 1.0000x reference)
//
#include <hip/hip_runtime.h>
#include <hip/hip_bf16.h>
#include <stdint.h>

#define BB   8192
#define NN   50
#define DD   64
#define TDD  16

__device__ __forceinline__ float bf_lo(uint32_t w) { return __uint_as_float(w << 16); }
__device__ __forceinline__ float bf_hi(uint32_t w) { return __uint_as_float(w & 0xffff0000u); }
__device__ __forceinline__ float bf16u(uint16_t u) { return __uint_as_float(((uint32_t)u) << 16); }

__device__ __forceinline__ uint32_t f2bf_bits(float f) {
    uint32_t u = __float_as_uint(f);
    u += 0x7fffu + ((u >> 16) & 1u);   // RNE
    return u >> 16;
}

__device__ __forceinline__ float fsig(float x)  { return 1.0f / (1.0f + __expf(-x)); }
__device__ __forceinline__ float ftanhf(float x){ return 1.0f - 2.0f / (__expf(2.0f * x) + 1.0f); }

// One wave = one (side, b) item. 4 waves/block, block side-uniform.
// LDS: GRU weights packed bf16x2, rows 0..191 = W_ih, 192..383 = W_hh, row stride 33 u32.
__global__ __launch_bounds__(256, 2)
void dygkt_kernel(const float* __restrict__ nodef, const float* __restrict__ edgef,
                  const int* __restrict__ src_ids, const int* __restrict__ dst_ids,
                  const float* __restrict__ times,
                  const int* __restrict__ s_nids, const int* __restrict__ s_eids,
                  const float* __restrict__ s_ts,
                  const int* __restrict__ d_nids, const int* __restrict__ d_eids,
                  const float* __restrict__ d_ts,
                  const float* __restrict__ W_feat, const float* __restrict__ b_feat,
                  const float* __restrict__ W_edge, const float* __restrict__ b_edge,
                  const float* __restrict__ W_time, const float* __restrict__ b_time,
                  const float* __restrict__ W_struct, const float* __restrict__ b_struct,
                  const float* __restrict__ W_out, const float* __restrict__ b_out,
                  const float* __restrict__ time_w, const float* __restrict__ time_b,
                  const float* __restrict__ sWih, const float* __restrict__ sWhh,
                  const float* __restrict__ sbih, const float* __restrict__ sbhh,
                  const float* __restrict__ dWih, const float* __restrict__ dWhh,
                  const float* __restrict__ dbih, const float* __restrict__ dbhh,
                  float* __restrict__ out)
{
    __shared__ uint32_t gw[384 * 33];      // 50688 B
    __shared__ uint16_t wf[64 * 64];       //  8192 B
    __shared__ uint16_t wt[16 * 64];       //  2048 B
    __shared__ float    tw_sh[16], tb_sh[16];
    __shared__ float    nf_sh[4][64];      //  1024 B
    __shared__ float2   xh_sh[4][64];      //  2048 B

    const int tid  = threadIdx.x;
    const int wave = tid >> 6;
    const int lane = tid & 63;
    const int item = blockIdx.x * 4 + wave;      // 0..16383 ; blocks are side-uniform
    const bool is_src = (item < BB);
    const int b = is_src ? item : (item - BB);

    // ---- stage weights into LDS ----
    const float* Wih = is_src ? sWih : dWih;
    const float* Whh = is_src ? sWhh : dWhh;
    for (int p = tid; p < 384 * 32; p += 256) {
        int r = p >> 5, k2 = p & 31;
        const float* srcrow = (r < 192) ? (Wih + r * 64) : (Whh + (r - 192) * 64);
        uint32_t lo = f2bf_bits(srcrow[2 * k2]);
        uint32_t hi = f2bf_bits(srcrow[2 * k2 + 1]);
        gw[r * 33 + k2] = lo | (hi << 16);
    }
    for (int p = tid; p < 64 * 64; p += 256) wf[p] = (uint16_t)f2bf_bits(W_feat[p]);
    for (int p = tid; p < 16 * 64; p += 256) wt[p] = (uint16_t)f2bf_bits(W_time[p]);
    if (tid < 16) { tw_sh[tid] = time_w[tid]; tb_sh[tid] = time_b[tid]; }
    __syncthreads();

    // ---- per-lane constants ----
    const float bfeatL = b_feat[lane];
    const float wedgeL = W_edge[lane];
    const float bedgeL = b_edge[lane];
    const float btimeL = b_time[lane];
    const float wstrL  = W_struct[lane];
    const float bstrL  = b_struct[lane];
    const float boutL  = b_out[lane];
    const float* bih = is_src ? sbih : dbih;
    const float* bhh = is_src ? sbhh : dbhh;
    const float bih0 = bih[lane], bih1 = bih[64 + lane], bih2 = bih[128 + lane];
    const float bhh0 = bhh[lane], bhh1 = bhh[64 + lane], bhh2 = bhh[128 + lane];

    const int   sid = src_ids[b];
    const int   did = dst_ids[b];
    const float tq  = times[b];
    const int   other_id  = is_src ? did : sid;     // co-occurrence target
    const float dst_skill = nodef[(size_t)did * 64];  // used by src blocks
    const int*   nbr_n = is_src ? (s_nids + (size_t)b * NN) : (d_nids + (size_t)b * NN);
    const int*   nbr_e = is_src ? (s_eids + (size_t)b * NN) : (d_eids + (size_t)b * NN);
    const float* nbr_t = is_src ? (s_ts   + (size_t)b * NN) : (d_ts   + (size_t)b * NN);

    // prime prefetch for t = 0
    int   nid = nbr_n[0];
    float ts  = nbr_t[0];
    float e0  = edgef[(size_t)nbr_e[0] * 4];
    float nfv = is_src ? nodef[(size_t)nid * 64 + lane] : 0.0f;

    float h = 0.0f;
    const uint32_t* w0 = gw + (size_t)lane * 33;          // W_ih rows d, 64+d, 128+d
    const uint32_t* w1 = gw + (size_t)(64  + lane) * 33;
    const uint32_t* w2 = gw + (size_t)(128 + lane) * 33;
    const uint32_t* w3 = gw + (size_t)(192 + lane) * 33;  // W_hh rows
    const uint32_t* w4 = gw + (size_t)(256 + lane) * 33;
    const uint32_t* w5 = gw + (size_t)(320 + lane) * 33;
    const float2* xhp = xh_sh[wave];

    for (int t = 0; t < NN; ++t) {
        // prefetch next step's gathers
        int nid_n = 0; float ts_n = 0.0f, e0_n = 0.0f, nfv_n = 0.0f;
        if (t + 1 < NN) {
            nid_n = nbr_n[t + 1];
            ts_n  = nbr_t[t + 1];
            e0_n  = edgef[(size_t)nbr_e[t + 1] * 4];
            if (is_src) nfv_n = nodef[(size_t)nid_n * 64 + lane];
        }

        float x;
        if (is_src) {
            nf_sh[wave][lane] = nfv;
            __syncthreads();
            float acc = bfeatL;
            #pragma unroll 8
            for (int k = 0; k < 64; ++k)
                acc += nf_sh[wave][k] * bf16u(wf[k * 64 + lane]);
            float nskill = nf_sh[wave][0];
            float sf = ((nskill == dst_skill) ? 1.0f : 0.0f) +
                       ((nid == other_id)     ? 1.0f : 0.0f);
            x = acc + sf * wstrL + 2.0f * bstrL;
        } else {
            float sf = (nid == other_id) ? 1.0f : 0.0f;
            x = sf * wstrL + bstrL;
        }

        // time encoding
        float delta = tq - ts;
        float tacc = btimeL;
        #pragma unroll
        for (int j = 0; j < TDD; ++j) {
            float c = __cosf(delta * tw_sh[j] + tb_sh[j]);
            tacc += c * bf16u(wt[j * 64 + lane]);
        }
        x += tacc + e0 * wedgeL + bedgeL;

        // GRU step
        xh_sh[wave][lane] = make_float2(x, h);
        __syncthreads();
        float gi0 = bih0, gi1 = bih1, gi2 = bih2;
        float gh0 = bhh0, gh1 = bhh1, gh2 = bhh2;
        #pragma unroll 8
        for (int k2 = 0; k2 < 32; ++k2) {
            float2 a = xhp[2 * k2];
            float2 c = xhp[2 * k2 + 1];
            uint32_t w;
            w = w0[k2]; gi0 += bf_lo(w) * a.x + bf_hi(w) * c.x;
            w = w1[k2]; gi1 += bf_lo(w) * a.x + bf_hi(w) * c.x;
            w = w2[k2]; gi2 += bf_lo(w) * a.x + bf_hi(w) * c.x;
            w = w3[k2]; gh0 += bf_lo(w) * a.y + bf_hi(w) * c.y;
            w = w4[k2]; gh1 += bf_lo(w) * a.y + bf_hi(w) * c.y;
            w = w5[k2]; gh2 += bf_lo(w) * a.y + bf_hi(w) * c.y;
        }
        float r = fsig(gi0 + gh0);
        float z = fsig(gi1 + gh1);
        float n = ftanhf(gi2 + r * gh2);
        h = (1.0f - z) * n + z * h;
        __syncthreads();

        nid = nid_n; ts = ts_n; e0 = e0_n; nfv = nfv_n;
    }

    // ---- tail (query position N): edge_f(eid=0) + time_f(delta=0) [+ node_f for dst] ----
    float tacc = btimeL;
    #pragma unroll
    for (int j = 0; j < TDD; ++j)
        tacc += __cosf(tb_sh[j]) * bf16u(wt[j * 64 + lane]);
    float tail = tacc + edgef[0] * wedgeL + bedgeL;

    if (!is_src) {
        nf_sh[wave][lane] = nodef[(size_t)did * 64 + lane];
        __syncthreads();
        float acc = bfeatL;
        #pragma unroll 8
        for (int k = 0; k < 64; ++k)
            acc += nf_sh[wave][k] * bf16u(wf[k * 64 + lane]);
        tail += acc;
    }

    float emb = h + tail;

    // out = emb @ W_out + b_out   (fp32 weights from global, L1-resident)
    xh_sh[wave][lane].x = emb;
    __syncthreads();
    float acc = boutL;
    #pragma unroll 8
    for (int k = 0; k < 64; ++k)
        acc += xh_sh[wave][k].x * W_out[k * 64 + lane];

    out[(size_t)(is_src ? 0 : 1) * BB * 64 + (size_t)b * 64 + lane] = acc;
}

extern "C" void kernel_launch(void* const* d_in, const int* in_sizes, int n_in,
                              void* d_out, int out_size, void* d_ws, size_t ws_size,
                              hipStream_t stream) {
    (void)in_sizes; (void)n_in; (void)d_ws; (void)ws_size; (void)out_size;
    const float* nodef  = (const float*)d_in[0];
    const float* edgef  = (const float*)d_in[1];
    const int*   srcid  = (const int*)  d_in[2];
    const int*   dstid  = (const int*)  d_in[3];
    const float* times  = (const float*)d_in[4];
    const int*   s_nids = (const int*)  d_in[5];
    const int*   s_eids = (const int*)  d_in[6];
    const float* s_ts   = (const float*)d_in[7];
    const int*   d_nids = (const int*)  d_in[8];
    const int*   d_eids = (const int*)  d_in[9];
    const float* d_ts   = (const float*)d_in[10];
    const float* W_feat = (const float*)d_in[11];
    const float* b_feat = (const float*)d_in[12];
    const float* W_edge = (const float*)d_in[13];
    const float* b_edge = (const float*)d_in[14];
    const float* W_time = (const float*)d_in[15];
    const float* b_time = (const float*)d_in[16];
    const float* W_str  = (const float*)d_in[17];
    const float* b_str  = (const float*)d_in[18];
    const float* W_out  = (const float*)d_in[19];
    const float* b_out  = (const float*)d_in[20];
    const float* time_w = (const float*)d_in[21];
    const float* time_b = (const float*)d_in[22];
    const float* sWih   = (const float*)d_in[23];
    const float* sWhh   = (const float*)d_in[24];
    const float* sbih   = (const float*)d_in[25];
    const float* sbhh   = (const float*)d_in[26];
    const float* dWih   = (const float*)d_in[27];
    const float* dWhh   = (const float*)d_in[28];
    const float* dbih   = (const float*)d_in[29];
    const float* dbhh   = (const float*)d_in[30];

    dim3 grid(4096), block(256);
    dygkt_kernel<<<grid, block, 0, stream>>>(
        nodef, edgef, srcid, dstid, times,
        s_nids, s_eids, s_ts, d_nids, d_eids, d_ts,
        W_feat, b_feat, W_edge, b_edge, W_time, b_time,
        W_str, b_str, W_out, b_out, time_w, time_b,
        sWih, sWhh, sbih, sbhh, dWih, dWhh, dbih, dbhh,
        (float*)d_out);
}

// Round 2
// 922.481 us; speedup vs baseline: 2.2650x; 2.2650x over previous
//
#include <hip/hip_runtime.h>
#include <stdint.h>

#define BB 8192
#define NN 50

typedef _Float16 h2t __attribute__((ext_vector_type(2)));

__device__ __forceinline__ float fdot2f(uint32_t a, uint32_t b, float c) {
#if __has_builtin(__builtin_amdgcn_fdot2)
    typedef __fp16 v2h __attribute__((ext_vector_type(2)));
    v2h av, bv; __builtin_memcpy(&av, &a, 4); __builtin_memcpy(&bv, &b, 4);
    return __builtin_amdgcn_fdot2(av, bv, c, false);
#else
    h2t ah, bh; __builtin_memcpy(&ah, &a, 4); __builtin_memcpy(&bh, &b, 4);
    return c + (float)ah.x * (float)bh.x + (float)ah.y * (float)bh.y;
#endif
}

__device__ __forceinline__ float dot4(uint4 w, uint4 v, float acc) {
    acc = fdot2f(w.x, v.x, acc); acc = fdot2f(w.y, v.y, acc);
    acc = fdot2f(w.z, v.z, acc); acc = fdot2f(w.w, v.w, acc);
    return acc;
}

__device__ __forceinline__ uint32_t pk2u(float a, float b) {
    auto p = __builtin_amdgcn_cvt_pkrtz(a, b);
    uint32_t u; __builtin_memcpy(&u, &p, 4); return u;
}

__device__ __forceinline__ float fsig(float x)   { return 1.0f / (1.0f + __expf(-x)); }
__device__ __forceinline__ float ftanhf(float x) { return 1.0f - 2.0f / (__expf(2.0f * x) + 1.0f); }

// Block = 256 thr = 4 waves; each wave owns 4 items (one side). Blocks 0..511 src, 512..1023 dst.
// W_hh rows live in 96 VGPRs/lane; W_ih / W_feat / W_time in LDS as lane-contiguous b128 chunks.
// All in-loop LDS traffic is wave-private (DS ops complete in order per wave) -> no barriers.
__global__ __launch_bounds__(256, 2)
void dygkt2(const float* __restrict__ nodef, const float* __restrict__ edgef,
            const int* __restrict__ src_ids, const int* __restrict__ dst_ids,
            const float* __restrict__ times,
            const int* __restrict__ s_nids, const int* __restrict__ s_eids,
            const float* __restrict__ s_ts,
            const int* __restrict__ d_nids, const int* __restrict__ d_eids,
            const float* __restrict__ d_ts,
            const float* __restrict__ W_feat, const float* __restrict__ b_feat,
            const float* __restrict__ W_edge, const float* __restrict__ b_edge,
            const float* __restrict__ W_time, const float* __restrict__ b_time,
            const float* __restrict__ W_struct, const float* __restrict__ b_struct,
            const float* __restrict__ W_out, const float* __restrict__ b_out,
            const float* __restrict__ time_w, const float* __restrict__ time_b,
            const float* __restrict__ sWih, const float* __restrict__ sWhh,
            const float* __restrict__ sbih, const float* __restrict__ sbhh,
            const float* __restrict__ dWih, const float* __restrict__ dWhh,
            const float* __restrict__ dbih, const float* __restrict__ dbhh,
            float* __restrict__ out)
{
    __shared__ uint4 gw4[6 * 8 * 64];     // 49152 B: [(g*8+c)*64 + lane], g 0..2 Wih, 3..5 Whh
    __shared__ uint4 wf4[8 * 64];         //  8192 B: k-pair chunks of W_feat
    __shared__ uint4 wt4[2 * 64];         //  2048 B
    __shared__ float tw_sh[16], tb_sh[16];
    __shared__ uint4 xhq[4][2][4][8];     //  4096 B: [wave][x/h][item][chunk]
    __shared__ uint4 cq[4][4][2];         //   512 B: [wave][item][chunk] cos pairs

    const int tid = threadIdx.x, wave = tid >> 6, lane = tid & 63;
    const bool is_src = blockIdx.x < 512;
    const int ib0 = (blockIdx.x & 511) * 16 + wave * 4;   // batch index base for this wave

    const float* Wih = is_src ? sWih : dWih;
    const float* Whh = is_src ? sWhh : dWhh;

    // ---- stage weights (coalesced reads, fp16 pair-packed) ----
    for (int q = tid; q < 6 * 8 * 64; q += 256) {
        int d = q & 63, c = (q >> 6) & 7, g = q >> 9;
        const float* row = ((g < 3) ? (Wih + (g * 64 + d) * 64) : (Whh + ((g - 3) * 64 + d) * 64)) + c * 8;
        uint4 v; v.x = pk2u(row[0], row[1]); v.y = pk2u(row[2], row[3]);
        v.z = pk2u(row[4], row[5]); v.w = pk2u(row[6], row[7]);
        gw4[q] = v;
    }
    for (int q = tid; q < 8 * 64; q += 256) {
        int d = q & 63, c = q >> 6;
        const float* p = W_feat + c * 8 * 64 + d;
        uint4 v; v.x = pk2u(p[0], p[64]); v.y = pk2u(p[128], p[192]);
        v.z = pk2u(p[256], p[320]); v.w = pk2u(p[384], p[448]);
        wf4[q] = v;
    }
    for (int q = tid; q < 2 * 64; q += 256) {
        int d = q & 63, c = q >> 6;
        const float* p = W_time + c * 8 * 64 + d;
        uint4 v; v.x = pk2u(p[0], p[64]); v.y = pk2u(p[128], p[192]);
        v.z = pk2u(p[256], p[320]); v.w = pk2u(p[384], p[448]);
        wt4[q] = v;
    }
    if (tid < 16) { tw_sh[tid] = time_w[tid]; tb_sh[tid] = time_b[tid]; }
    __syncthreads();   // the only block barrier

    // ---- W_hh rows -> registers (96 VGPRs) ----
    uint4 whh0[8], whh1[8], whh2[8];
    #pragma unroll
    for (int c = 0; c < 8; ++c) {
        whh0[c] = gw4[(24 + c) * 64 + lane];
        whh1[c] = gw4[(32 + c) * 64 + lane];
        whh2[c] = gw4[(40 + c) * 64 + lane];
    }

    // ---- per-lane constants ----
    const float bfeatL = b_feat[lane];
    const float wedgeL = W_edge[lane];
    const float bedgeL = b_edge[lane];
    const float btimeL = b_time[lane];
    const float wstrL  = W_struct[lane];
    const float bstrL  = b_struct[lane];
    const float boutL  = b_out[lane];
    const float twL = tw_sh[lane & 15], tbL = tb_sh[lane & 15];
    const float* bih = is_src ? sbih : dbih;
    const float* bhh = is_src ? sbhh : dbhh;
    const float bih0 = bih[lane], bih1 = bih[64 + lane], bih2 = bih[128 + lane];
    const float bhh0 = bhh[lane], bhh1 = bhh[64 + lane], bhh2 = bhh[128 + lane];

    // ---- per-item setup ----
    const int*   pn[4]; const int* pe[4]; const float* pt[4];
    int   oid[4]; float tq[4], dskill[4]; int didv[4];
    #pragma unroll
    for (int i = 0; i < 4; ++i) {
        int b = ib0 + i;
        int sid = src_ids[b], did = dst_ids[b];
        didv[i] = did;
        oid[i] = is_src ? did : sid;
        tq[i]  = times[b];
        if (is_src) dskill[i] = nodef[(size_t)did * 64];
        pn[i] = (is_src ? s_nids : d_nids) + (size_t)b * NN;
        pe[i] = (is_src ? s_eids : d_eids) + (size_t)b * NN;
        pt[i] = (is_src ? s_ts   : d_ts)   + (size_t)b * NN;
    }

    // prime prefetch (t=0)
    int nid[4]; float tsc[4], e0[4], nfv[4], h[4];
    #pragma unroll
    for (int i = 0; i < 4; ++i) {
        nid[i] = pn[i][0]; tsc[i] = pt[i][0];
        e0[i]  = edgef[(size_t)pe[i][0] * 4];
        nfv[i] = is_src ? nodef[(size_t)nid[i] * 64 + lane] : 0.0f;
        h[i] = 0.0f;
    }

    const int jj = lane & 31;

    for (int t = 0; t < NN; ++t) {
        // ---- prefetch next step ----
        int nidn[4]; float tsn[4], e0n[4], nfn[4];
        if (t + 1 < NN) {
            #pragma unroll
            for (int i = 0; i < 4; ++i) {
                nidn[i] = pn[i][t + 1]; tsn[i] = pt[i][t + 1];
                e0n[i]  = edgef[(size_t)pe[i][t + 1] * 4];
                nfn[i]  = is_src ? nodef[(size_t)nidn[i] * 64 + lane] : 0.0f;
            }
        } else {
            #pragma unroll
            for (int i = 0; i < 4; ++i) { nidn[i] = 0; tsn[i] = 0.f; e0n[i] = 0.f; nfn[i] = 0.f; }
        }

        float x[4], facc[4];
        // ---- node-feature projection (src only; dot2 from LDS fp16) ----
        if (is_src) {
            #pragma unroll
            for (int i = 0; i < 4; ++i) {
                float s0 = __shfl(nfv[i], 2 * jj), s1 = __shfl(nfv[i], 2 * jj + 1);
                ((uint32_t*)&xhq[wave][0][i][0])[jj] = pk2u(s0, s1);   // lanes>=32 dup-write same data
            }
            #pragma unroll
            for (int i = 0; i < 4; ++i) facc[i] = bfeatL;
            #pragma unroll
            for (int c = 0; c < 8; ++c) {
                uint4 WF = wf4[c * 64 + lane];
                #pragma unroll
                for (int i = 0; i < 4; ++i) facc[i] = dot4(WF, xhq[wave][0][i][c], facc[i]);
            }
        }

        // ---- time encoding: 64 lanes compute the 4x16 cos grid, pack to fp16 pairs ----
        {
            int ii = lane >> 4;
            float dsel = (ii == 0) ? (tq[0] - tsc[0]) : (ii == 1) ? (tq[1] - tsc[1])
                       : (ii == 2) ? (tq[2] - tsc[2]) : (tq[3] - tsc[3]);
            float cv = __cosf(dsel * twL + tbL);
            int jj2 = lane & 7, ic = (lane >> 3) & 3;
            float cs0 = __shfl(cv, ic * 16 + 2 * jj2), cs1 = __shfl(cv, ic * 16 + 2 * jj2 + 1);
            ((uint32_t*)&cq[wave][ic][0])[jj2] = pk2u(cs0, cs1);
        }
        float ta[4];
        #pragma unroll
        for (int i = 0; i < 4; ++i) ta[i] = btimeL;
        #pragma unroll
        for (int c = 0; c < 2; ++c) {
            uint4 WT = wt4[c * 64 + lane];
            #pragma unroll
            for (int i = 0; i < 4; ++i) ta[i] = dot4(WT, cq[wave][i][c], ta[i]);
        }

        // ---- assemble x ----
        #pragma unroll
        for (int i = 0; i < 4; ++i) {
            if (is_src) {
                float nskill = __shfl(nfv[i], 0);
                float sf = ((nskill == dskill[i]) ? 1.0f : 0.0f) + ((nid[i] == oid[i]) ? 1.0f : 0.0f);
                x[i] = facc[i] + sf * wstrL + 2.0f * bstrL + ta[i] + e0[i] * wedgeL + bedgeL;
            } else {
                float sf = (nid[i] == oid[i]) ? 1.0f : 0.0f;
                x[i] = sf * wstrL + bstrL + ta[i] + e0[i] * wedgeL + bedgeL;
            }
        }

        // ---- pack x (fp16) and h (fp16 copy; fp32 master stays in regs) ----
        #pragma unroll
        for (int i = 0; i < 4; ++i) {
            float xs0 = __shfl(x[i], 2 * jj), xs1 = __shfl(x[i], 2 * jj + 1);
            float hs0 = __shfl(h[i], 2 * jj), hs1 = __shfl(h[i], 2 * jj + 1);
            if (lane < 32) ((uint32_t*)&xhq[wave][0][i][0])[jj] = pk2u(xs0, xs1);
            else           ((uint32_t*)&xhq[wave][1][i][0])[jj] = pk2u(hs0, hs1);
        }

        // ---- GRU gates: ih from LDS, hh from registers ----
        float gi0[4], gi1[4], gi2[4], gh0[4], gh1[4], gh2[4];
        #pragma unroll
        for (int i = 0; i < 4; ++i) {
            gi0[i] = bih0; gi1[i] = bih1; gi2[i] = bih2;
            gh0[i] = bhh0; gh1[i] = bhh1; gh2[i] = bhh2;
        }
        #pragma unroll
        for (int c = 0; c < 8; ++c) {
            uint4 X[4], H[4];
            #pragma unroll
            for (int i = 0; i < 4; ++i) { X[i] = xhq[wave][0][i][c]; H[i] = xhq[wave][1][i][c]; }
            uint4 Wg;
            Wg = gw4[c * 64 + lane];
            #pragma unroll
            for (int i = 0; i < 4; ++i) gi0[i] = dot4(Wg, X[i], gi0[i]);
            Wg = gw4[(8 + c) * 64 + lane];
            #pragma unroll
            for (int i = 0; i < 4; ++i) gi1[i] = dot4(Wg, X[i], gi1[i]);
            Wg = gw4[(16 + c) * 64 + lane];
            #pragma unroll
            for (int i = 0; i < 4; ++i) gi2[i] = dot4(Wg, X[i], gi2[i]);
            #pragma unroll
            for (int i = 0; i < 4; ++i) {
                gh0[i] = dot4(whh0[c], H[i], gh0[i]);
                gh1[i] = dot4(whh1[c], H[i], gh1[i]);
                gh2[i] = dot4(whh2[c], H[i], gh2[i]);
            }
        }
        #pragma unroll
        for (int i = 0; i < 4; ++i) {
            float r = fsig(gi0[i] + gh0[i]);
            float z = fsig(gi1[i] + gh1[i]);
            float n = ftanhf(gi2[i] + r * gh2[i]);
            h[i] = n + z * (h[i] - n);
        }

        #pragma unroll
        for (int i = 0; i < 4; ++i) { nid[i] = nidn[i]; tsc[i] = tsn[i]; e0[i] = e0n[i]; nfv[i] = nfn[i]; }
    }

    // ---- tail: time proj at delta=0 + edge proj of edge id 0 ----
    {
        float cv0 = __cosf(tbL);
        float c0s0 = __shfl(cv0, 2 * (lane & 7)), c0s1 = __shfl(cv0, 2 * (lane & 7) + 1);
        ((uint32_t*)&cq[wave][0][0])[lane & 7] = pk2u(c0s0, c0s1);
    }
    float ta0 = btimeL;
    #pragma unroll
    for (int c = 0; c < 2; ++c) ta0 = dot4(wt4[c * 64 + lane], cq[wave][0][c], ta0);
    const float tail = ta0 + edgef[0] * wedgeL + bedgeL;

    float emb[4];
    if (is_src) {
        #pragma unroll
        for (int i = 0; i < 4; ++i) emb[i] = h[i] + tail;
    } else {
        // dst tail adds node-feature projection of did
        float fa[4];
        #pragma unroll
        for (int i = 0; i < 4; ++i) {
            float nfd = nodef[(size_t)didv[i] * 64 + lane];
            float s0 = __shfl(nfd, 2 * jj), s1 = __shfl(nfd, 2 * jj + 1);
            ((uint32_t*)&xhq[wave][0][i][0])[jj] = pk2u(s0, s1);
            fa[i] = bfeatL;
        }
        #pragma unroll
        for (int c = 0; c < 8; ++c) {
            uint4 WF = wf4[c * 64 + lane];
            #pragma unroll
            for (int i = 0; i < 4; ++i) fa[i] = dot4(WF, xhq[wave][0][i][c], fa[i]);
        }
        #pragma unroll
        for (int i = 0; i < 4; ++i) emb[i] = h[i] + tail + fa[i];
    }

    // ---- output projection: out = emb @ W_out + b_out (fp32, W_out L1-resident) ----
    float* ebuf = (float*)&xhq[wave][0][0][0];   // 1 KB per wave, reuse
    #pragma unroll
    for (int i = 0; i < 4; ++i) ebuf[i * 64 + lane] = emb[i];
    float oa[4] = {boutL, boutL, boutL, boutL};
    #pragma unroll 8
    for (int k = 0; k < 64; ++k) {
        float wv = W_out[k * 64 + lane];
        #pragma unroll
        for (int i = 0; i < 4; ++i) oa[i] += ebuf[i * 64 + k] * wv;
    }
    const size_t base = is_src ? 0 : (size_t)BB * 64;
    #pragma unroll
    for (int i = 0; i < 4; ++i)
        out[base + (size_t)(ib0 + i) * 64 + lane] = oa[i];
}

extern "C" void kernel_launch(void* const* d_in, const int* in_sizes, int n_in,
                              void* d_out, int out_size, void* d_ws, size_t ws_size,
                              hipStream_t stream) {
    (void)in_sizes; (void)n_in; (void)d_ws; (void)ws_size; (void)out_size;
    const float* nodef  = (const float*)d_in[0];
    const float* edgef  = (const float*)d_in[1];
    const int*   srcid  = (const int*)  d_in[2];
    const int*   dstid  = (const int*)  d_in[3];
    const float* times  = (const float*)d_in[4];
    const int*   s_nids = (const int*)  d_in[5];
    const int*   s_eids = (const int*)  d_in[6];
    const float* s_ts   = (const float*)d_in[7];
    const int*   d_nids = (const int*)  d_in[8];
    const int*   d_eids = (const int*)  d_in[9];
    const float* d_ts   = (const float*)d_in[10];
    const float* W_feat = (const float*)d_in[11];
    const float* b_feat = (const float*)d_in[12];
    const float* W_edge = (const float*)d_in[13];
    const float* b_edge = (const float*)d_in[14];
    const float* W_time = (const float*)d_in[15];
    const float* b_time = (const float*)d_in[16];
    const float* W_str  = (const float*)d_in[17];
    const float* b_str  = (const float*)d_in[18];
    const float* W_out  = (const float*)d_in[19];
    const float* b_out  = (const float*)d_in[20];
    const float* time_w = (const float*)d_in[21];
    const float* time_b = (const float*)d_in[22];
    const float* sWih   = (const float*)d_in[23];
    const float* sWhh   = (const float*)d_in[24];
    const float* sbih   = (const float*)d_in[25];
    const float* sbhh   = (const float*)d_in[26];
    const float* dWih   = (const float*)d_in[27];
    const float* dWhh   = (const float*)d_in[28];
    const float* dbih   = (const float*)d_in[29];
    const float* dbhh   = (const float*)d_in[30];

    dim3 grid(1024), block(256);
    dygkt2<<<grid, block, 0, stream>>>(
        nodef, edgef, srcid, dstid, times,
        s_nids, s_eids, s_ts, d_nids, d_eids, d_ts,
        W_feat, b_feat, W_edge, b_edge, W_time, b_time,
        W_str, b_str, W_out, b_out, time_w, time_b,
        sWih, sWhh, sbih, sbhh, dWih, dWhh, dbih, dbhh,
        (float*)d_out);
}

// Round 3
// 297.412 us; speedup vs baseline: 7.0253x; 3.1017x over previous
//
#include <hip/hip_runtime.h>
#include <stdint.h>

#define BB 8192
#define NN 50

typedef _Float16 half8 __attribute__((ext_vector_type(8)));
typedef float floatx4 __attribute__((ext_vector_type(4)));

union FragU { uint4 u; half8 h; };
static __device__ __forceinline__ half8 u2h(uint4 u) { FragU f; f.u = u; return f.h; }

static __device__ __forceinline__ uint32_t pk2u(float a, float b) {
    auto p = __builtin_amdgcn_cvt_pkrtz(a, b);
    uint32_t u; __builtin_memcpy(&u, &p, 4); return u;
}

#define MFMA(A, B, C) __builtin_amdgcn_mfma_f32_16x16x32_f16((A), (B), (C), 0, 0, 0)

static __device__ __forceinline__ float fsig(float x)   { return 1.0f / (1.0f + __expf(-x)); }
static __device__ __forceinline__ float ftanhf(float x) { return 1.0f - 2.0f / (__expf(2.0f * x) + 1.0f); }

// One wave = 16 items (one side). 256 blocks x 256 threads; blocks 0..127 src, 128..255 dst.
// Orientation: D[m=outdim][n=item] = A[W rows, in VGPRs] * B[activations^T].
// A-frag: A[m=lane&15][k=8*(lane>>4)+j]; B-frag: B[k=8*(lane>>4)+j][n=lane&15];
// C/D: col(n)=lane&15, row(m)=4*(lane>>4)+reg  (m89-verified).
__global__ __launch_bounds__(256, 1)
void dygkt3(const float* __restrict__ nodef, const float* __restrict__ edgef,
            const int* __restrict__ src_ids, const int* __restrict__ dst_ids,
            const float* __restrict__ times,
            const int* __restrict__ s_nids, const int* __restrict__ s_eids,
            const float* __restrict__ s_ts,
            const int* __restrict__ d_nids, const int* __restrict__ d_eids,
            const float* __restrict__ d_ts,
            const float* __restrict__ W_feat, const float* __restrict__ b_feat,
            const float* __restrict__ W_edge, const float* __restrict__ b_edge,
            const float* __restrict__ W_time, const float* __restrict__ b_time,
            const float* __restrict__ W_str,  const float* __restrict__ b_str,
            const float* __restrict__ W_out,  const float* __restrict__ b_out,
            const float* __restrict__ time_w, const float* __restrict__ time_b,
            const float* __restrict__ sWih, const float* __restrict__ sWhh,
            const float* __restrict__ sbih, const float* __restrict__ sbhh,
            const float* __restrict__ dWih, const float* __restrict__ dWhh,
            const float* __restrict__ dbih, const float* __restrict__ dbhh,
            float* __restrict__ out)
{
    __shared__ uint4 wfA[8][64];                        // W_feat^T A-frags [kh*4+mt][lane], 8 KB
    __shared__ uint4 woA[8][64];                        // W_out^T  A-frags, 8 KB
    __shared__ __align__(16) _Float16 xbuf[4][16 * 72]; // per-wave x^T staging, 4x2304 B
    __shared__ __align__(16) _Float16 hbuf[4][16 * 72]; // per-wave h^T staging

    const int tid = threadIdx.x, wave = tid >> 6, lane = tid & 63;
    const int g = lane >> 4, i16 = lane & 15;
    const bool is_src = blockIdx.x < 128;
    const int ib0 = (int)(blockIdx.x & 127) * 64 + wave * 16;
    const int b = ib0 + i16;                            // this lane's item

    // ---- stage W_feat^T / W_out^T A-frags into LDS; zero hbuf ----
    for (int q = tid; q < 512; q += 256) {
        int l = q & 63, tt = q >> 6;
        int kh = tt >> 2, mt = tt & 3, gg = l >> 4, ii = l & 15;
        float v[8], w[8];
        #pragma unroll
        for (int j = 0; j < 8; ++j) {
            int k = 32 * kh + 8 * gg + j, m = 16 * mt + ii;
            v[j] = W_feat[k * 64 + m];
            w[j] = W_out[k * 64 + m];
        }
        wfA[tt][l] = make_uint4(pk2u(v[0],v[1]), pk2u(v[2],v[3]), pk2u(v[4],v[5]), pk2u(v[6],v[7]));
        woA[tt][l] = make_uint4(pk2u(w[0],w[1]), pk2u(w[2],w[3]), pk2u(w[4],w[5]), pk2u(w[6],w[7]));
    }
    for (int q = tid; q < 4 * 16 * 72 / 2; q += 256) ((uint32_t*)hbuf)[q] = 0;
    __syncthreads();   // only block barrier

    // ---- GRU weight A-frags -> VGPRs (rows 0..63 r, 64..127 z, 128..191 n) ----
    const float* WI = is_src ? sWih : dWih;
    const float* WH = is_src ? sWhh : dWhh;
    uint4 wih[12][2], whh[12][2];
    #pragma unroll
    for (int mt = 0; mt < 12; ++mt)
        #pragma unroll
        for (int kh = 0; kh < 2; ++kh) {
            const float* p = WI + (size_t)(16 * mt + i16) * 64 + 32 * kh + 8 * g;
            float4 a = *(const float4*)p, c = *(const float4*)(p + 4);
            wih[mt][kh] = make_uint4(pk2u(a.x,a.y), pk2u(a.z,a.w), pk2u(c.x,c.y), pk2u(c.z,c.w));
            const float* q = WH + (size_t)(16 * mt + i16) * 64 + 32 * kh + 8 * g;
            float4 e = *(const float4*)q, f = *(const float4*)(q + 4);
            whh[mt][kh] = make_uint4(pk2u(e.x,e.y), pk2u(e.z,e.w), pk2u(f.x,f.y), pk2u(f.z,f.w));
        }

    // ---- time/edge/struct/bias bundle A-frags (K rows 0..15 = W_time^T, 16 = W_edge,
    //      17 = W_struct, 18 = b_edge+b_time, 19 = side bundle, 20 = b_feat, 21..31 = 0) ----
    uint4 wtA[4];
    #pragma unroll
    for (int mt = 0; mt < 4; ++mt) {
        float v[8];
        #pragma unroll
        for (int j = 0; j < 8; ++j) {
            int k = 8 * g + j, dim = 16 * mt + i16;
            float x = 0.0f;
            if (k < 16)       x = W_time[k * 64 + dim];
            else if (k == 16) x = W_edge[dim];
            else if (k == 17) x = W_str[dim];
            else if (k == 18) x = b_edge[dim] + b_time[dim];
            else if (k == 19) x = is_src ? (b_feat[dim] + 2.0f * b_str[dim]) : b_str[dim];
            else if (k == 20) x = b_feat[dim];
            v[j] = x;
        }
        wtA[mt] = make_uint4(pk2u(v[0],v[1]), pk2u(v[2],v[3]), pk2u(v[4],v[5]), pk2u(v[6],v[7]));
    }

    // ---- gate bias C-init vectors ----
    const float* BI = is_src ? sbih : dbih;
    const float* BH = is_src ? sbhh : dbhh;
    floatx4 brz[8], bin[4], bhn[4];
    #pragma unroll
    for (int mt = 0; mt < 8; ++mt) {
        floatx4 v;
        #pragma unroll
        for (int r = 0; r < 4; ++r) v[r] = BI[16 * mt + 4 * g + r] + BH[16 * mt + 4 * g + r];
        brz[mt] = v;
    }
    #pragma unroll
    for (int mt = 0; mt < 4; ++mt) {
        floatx4 vi, vh;
        #pragma unroll
        for (int r = 0; r < 4; ++r) {
            vi[r] = BI[128 + 16 * mt + 4 * g + r];
            vh[r] = BH[128 + 16 * mt + 4 * g + r];
        }
        bin[mt] = vi; bhn[mt] = vh;
    }

    // ---- per-lane (per-item) scalars ----
    const int* pn = (is_src ? s_nids : d_nids) + (size_t)b * NN;
    const int* pe = (is_src ? s_eids : d_eids) + (size_t)b * NN;
    const float* pt = (is_src ? s_ts : d_ts) + (size_t)b * NN;
    const float tqL = times[b];
    const int didL = dst_ids[b];
    const int oid = is_src ? didL : src_ids[b];
    const float dskill = is_src ? nodef[(size_t)didL * 64] : 0.0f;
    float twc[8], tbc[8];
    #pragma unroll
    for (int j = 0; j < 8; ++j) {
        int k = 8 * (g & 1) + j;
        twc[j] = time_w[k]; tbc[j] = time_b[k];
    }

    // ---- prime prefetch for t = 0 ----
    int nidC = pn[0], eidC = pe[0];
    float tsC = pt[0];
    float e0C = edgef[4 * (size_t)eidC];
    float4 nfa = {0,0,0,0}, nfb = {0,0,0,0}, nfc = {0,0,0,0}, nfd = {0,0,0,0};
    if (is_src) {
        const float* rp = nodef + (size_t)nidC * 64 + 8 * g;
        nfa = *(const float4*)rp;        nfb = *(const float4*)(rp + 4);
        nfc = *(const float4*)(rp + 32); nfd = *(const float4*)(rp + 36);
    }

    floatx4 hM[4] = {{0,0,0,0},{0,0,0,0},{0,0,0,0},{0,0,0,0}};
    const floatx4 z4 = {0,0,0,0};
    _Float16* xb = xbuf[wave];
    _Float16* hb = hbuf[wave];

    for (int t = 0; t < NN; ++t) {
        // scalar prefetch for t+1
        int nidN = 0, eidN = 0; float tsN = 0.0f;
        if (t + 1 < NN) { nidN = pn[t + 1]; eidN = pe[t + 1]; tsN = pt[t + 1]; }

        // ---- B-frag: [tenc(16) | e0, sf, 1, 1, 0...] ----
        float nsk = __shfl(nfa.x, i16);   // row[0] of this item's node row (src)
        float sf = ((nidC == oid) ? 1.0f : 0.0f) +
                   ((is_src && nsk == dskill) ? 1.0f : 0.0f);
        float delta = tqL - tsC;
        uint4 tb4;
        if (g < 2) {
            float cv[8];
            #pragma unroll
            for (int j = 0; j < 8; ++j) cv[j] = __cosf(delta * twc[j] + tbc[j]);
            tb4 = make_uint4(pk2u(cv[0],cv[1]), pk2u(cv[2],cv[3]), pk2u(cv[4],cv[5]), pk2u(cv[6],cv[7]));
        } else if (g == 2) {
            tb4 = make_uint4(pk2u(e0C, sf), pk2u(1.0f, 1.0f), 0u, 0u);
        } else {
            tb4 = make_uint4(0u, 0u, 0u, 0u);
        }
        half8 tB = u2h(tb4);

        // ---- x^T = [feat GEMM (src)] + time/edge/struct/bias GEMM ----
        floatx4 xacc[4];
        if (is_src) {
            uint4 nf0 = make_uint4(pk2u(nfa.x,nfa.y), pk2u(nfa.z,nfa.w), pk2u(nfb.x,nfb.y), pk2u(nfb.z,nfb.w));
            uint4 nf1 = make_uint4(pk2u(nfc.x,nfc.y), pk2u(nfc.z,nfc.w), pk2u(nfd.x,nfd.y), pk2u(nfd.z,nfd.w));
            half8 nB0 = u2h(nf0), nB1 = u2h(nf1);
            #pragma unroll
            for (int mt = 0; mt < 4; ++mt) {
                floatx4 a = MFMA(u2h(wfA[mt][lane]), nB0, z4);
                a = MFMA(u2h(wfA[4 + mt][lane]), nB1, a);
                xacc[mt] = MFMA(u2h(wtA[mt]), tB, a);
            }
        } else {
            #pragma unroll
            for (int mt = 0; mt < 4; ++mt) xacc[mt] = MFMA(u2h(wtA[mt]), tB, z4);
        }

        // ---- pack x -> LDS, read back as B-frags (wave-private, in-order) ----
        #pragma unroll
        for (int mt = 0; mt < 4; ++mt)
            *(uint2*)&xb[i16 * 72 + mt * 16 + 4 * g] =
                make_uint2(pk2u(xacc[mt][0], xacc[mt][1]), pk2u(xacc[mt][2], xacc[mt][3]));
        half8 xB0 = u2h(*(const uint4*)&xb[i16 * 72 + 8 * g]);
        half8 xB1 = u2h(*(const uint4*)&xb[i16 * 72 + 32 + 8 * g]);

        // ---- issue gathers for t+1 (hidden behind gate MFMAs) ----
        float e0N = 0.0f; float4 na = {0,0,0,0}, nb = {0,0,0,0}, nc = {0,0,0,0}, nd = {0,0,0,0};
        if (t + 1 < NN) {
            e0N = edgef[4 * (size_t)eidN];
            if (is_src) {
                const float* rp = nodef + (size_t)nidN * 64 + 8 * g;
                na = *(const float4*)rp;        nb = *(const float4*)(rp + 4);
                nc = *(const float4*)(rp + 32); nd = *(const float4*)(rp + 36);
            }
        }

        // ---- h B-frags from previous step ----
        half8 hB0 = u2h(*(const uint4*)&hb[i16 * 72 + 8 * g]);
        half8 hB1 = u2h(*(const uint4*)&hb[i16 * 72 + 32 + 8 * g]);

        // ---- gate GEMMs: r (tiles 0..3), z (4..7), n split ih/hh (8..11) ----
        floatx4 rg[4], zg[4], ia[4], ha[4];
        #pragma unroll
        for (int mt = 0; mt < 4; ++mt) {
            floatx4 a = MFMA(u2h(wih[mt][0]), xB0, brz[mt]);
            a = MFMA(u2h(wih[mt][1]), xB1, a);
            a = MFMA(u2h(whh[mt][0]), hB0, a);
            rg[mt] = MFMA(u2h(whh[mt][1]), hB1, a);
        }
        #pragma unroll
        for (int mt = 0; mt < 4; ++mt) {
            floatx4 a = MFMA(u2h(wih[4 + mt][0]), xB0, brz[4 + mt]);
            a = MFMA(u2h(wih[4 + mt][1]), xB1, a);
            a = MFMA(u2h(whh[4 + mt][0]), hB0, a);
            zg[mt] = MFMA(u2h(whh[4 + mt][1]), hB1, a);
        }
        #pragma unroll
        for (int mt = 0; mt < 4; ++mt) {
            floatx4 a = MFMA(u2h(wih[8 + mt][0]), xB0, bin[mt]);
            ia[mt] = MFMA(u2h(wih[8 + mt][1]), xB1, a);
            floatx4 c = MFMA(u2h(whh[8 + mt][0]), hB0, bhn[mt]);
            ha[mt] = MFMA(u2h(whh[8 + mt][1]), hB1, c);
        }

        // ---- elementwise gate math; h lives in C-layout registers ----
        #pragma unroll
        for (int mt = 0; mt < 4; ++mt)
            #pragma unroll
            for (int r = 0; r < 4; ++r) {
                float rr = fsig(rg[mt][r]);
                float zz = fsig(zg[mt][r]);
                float nn = ftanhf(ia[mt][r] + rr * ha[mt][r]);
                hM[mt][r] = nn + zz * (hM[mt][r] - nn);
            }

        // ---- h -> LDS for next step's B-frags ----
        #pragma unroll
        for (int mt = 0; mt < 4; ++mt)
            *(uint2*)&hb[i16 * 72 + mt * 16 + 4 * g] =
                make_uint2(pk2u(hM[mt][0], hM[mt][1]), pk2u(hM[mt][2], hM[mt][3]));

        nidC = nidN; eidC = eidN; tsC = tsN; e0C = e0N;
        nfa = na; nfb = nb; nfc = nc; nfd = nd;
    }

    // ---- tail: delta=0 time proj + edge(eid=0) proj [+ node_f(did) + b_feat for dst] ----
    float e00 = edgef[0];
    uint4 tt4;
    if (g < 2) {
        float cv[8];
        #pragma unroll
        for (int j = 0; j < 8; ++j) cv[j] = __cosf(tbc[j]);
        tt4 = make_uint4(pk2u(cv[0],cv[1]), pk2u(cv[2],cv[3]), pk2u(cv[4],cv[5]), pk2u(cv[6],cv[7]));
    } else if (g == 2) {
        tt4 = make_uint4(pk2u(e00, 0.0f), pk2u(1.0f, 0.0f), pk2u(is_src ? 0.0f : 1.0f, 0.0f), 0u);
    } else {
        tt4 = make_uint4(0u, 0u, 0u, 0u);
    }
    half8 tT = u2h(tt4);

    floatx4 tacc[4];
    #pragma unroll
    for (int mt = 0; mt < 4; ++mt) tacc[mt] = MFMA(u2h(wtA[mt]), tT, z4);
    if (!is_src) {
        const float* rp = nodef + (size_t)didL * 64 + 8 * g;
        float4 da = *(const float4*)rp,        db = *(const float4*)(rp + 4);
        float4 dc = *(const float4*)(rp + 32), dd = *(const float4*)(rp + 36);
        uint4 d0 = make_uint4(pk2u(da.x,da.y), pk2u(da.z,da.w), pk2u(db.x,db.y), pk2u(db.z,db.w));
        uint4 d1 = make_uint4(pk2u(dc.x,dc.y), pk2u(dc.z,dc.w), pk2u(dd.x,dd.y), pk2u(dd.z,dd.w));
        #pragma unroll
        for (int mt = 0; mt < 4; ++mt) {
            tacc[mt] = MFMA(u2h(wfA[mt][lane]), u2h(d0), tacc[mt]);
            tacc[mt] = MFMA(u2h(wfA[4 + mt][lane]), u2h(d1), tacc[mt]);
        }
    }

    // ---- out = (h + tail) @ W_out + b_out via MFMA ----
    #pragma unroll
    for (int mt = 0; mt < 4; ++mt) {
        floatx4 e = hM[mt] + tacc[mt];
        *(uint2*)&xb[i16 * 72 + mt * 16 + 4 * g] =
            make_uint2(pk2u(e[0], e[1]), pk2u(e[2], e[3]));
    }
    half8 eB0 = u2h(*(const uint4*)&xb[i16 * 72 + 8 * g]);
    half8 eB1 = u2h(*(const uint4*)&xb[i16 * 72 + 32 + 8 * g]);

    const size_t obase = (is_src ? 0 : (size_t)BB * 64) + (size_t)(ib0 + i16) * 64;
    #pragma unroll
    for (int mt = 0; mt < 4; ++mt) {
        floatx4 bo;
        #pragma unroll
        for (int r = 0; r < 4; ++r) bo[r] = b_out[16 * mt + 4 * g + r];
        floatx4 o = MFMA(u2h(woA[mt][lane]), eB0, bo);
        o = MFMA(u2h(woA[4 + mt][lane]), eB1, o);
        #pragma unroll
        for (int r = 0; r < 4; ++r)
            out[obase + 16 * mt + 4 * g + r] = o[r];
    }
}

extern "C" void kernel_launch(void* const* d_in, const int* in_sizes, int n_in,
                              void* d_out, int out_size, void* d_ws, size_t ws_size,
                              hipStream_t stream) {
    (void)in_sizes; (void)n_in; (void)d_ws; (void)ws_size; (void)out_size;
    const float* nodef  = (const float*)d_in[0];
    const float* edgef  = (const float*)d_in[1];
    const int*   srcid  = (const int*)  d_in[2];
    const int*   dstid  = (const int*)  d_in[3];
    const float* times  = (const float*)d_in[4];
    const int*   s_nids = (const int*)  d_in[5];
    const int*   s_eids = (const int*)  d_in[6];
    const float* s_ts   = (const float*)d_in[7];
    const int*   d_nids = (const int*)  d_in[8];
    const int*   d_eids = (const int*)  d_in[9];
    const float* d_ts   = (const float*)d_in[10];
    const float* W_feat = (const float*)d_in[11];
    const float* b_feat = (const float*)d_in[12];
    const float* W_edge = (const float*)d_in[13];
    const float* b_edge = (const float*)d_in[14];
    const float* W_time = (const float*)d_in[15];
    const float* b_time = (const float*)d_in[16];
    const float* W_str  = (const float*)d_in[17];
    const float* b_str  = (const float*)d_in[18];
    const float* W_out  = (const float*)d_in[19];
    const float* b_out  = (const float*)d_in[20];
    const float* time_w = (const float*)d_in[21];
    const float* time_b = (const float*)d_in[22];
    const float* sWih   = (const float*)d_in[23];
    const float* sWhh   = (const float*)d_in[24];
    const float* sbih   = (const float*)d_in[25];
    const float* sbhh   = (const float*)d_in[26];
    const float* dWih   = (const float*)d_in[27];
    const float* dWhh   = (const float*)d_in[28];
    const float* dbih   = (const float*)d_in[29];
    const float* dbhh   = (const float*)d_in[30];

    dim3 grid(256), block(256);
    dygkt3<<<grid, block, 0, stream>>>(
        nodef, edgef, srcid, dstid, times,
        s_nids, s_eids, s_ts, d_nids, d_eids, d_ts,
        W_feat, b_feat, W_edge, b_edge, W_time, b_time,
        W_str, b_str, W_out, b_out, time_w, time_b,
        sWih, sWhh, sbih, sbhh, dWih, dWhh, dbih, dbhh,
        (float*)d_out);
}